// Round 3
// baseline (287.036 us; speedup 1.0000x reference)
//
#include <hip/hip_runtime.h>
#include <hip/hip_bf16.h>
#include <hip/hip_fp16.h>
#include <stdint.h>

// Problem constants (B=2, T=2048, D=1024, H=16, hd=64)
#define B_    2
#define T_    2048
#define DM    1024
#define NH    16
#define HD    64
#define M_    (B_ * T_)      // 4096 rows of X
#define N_QKV (3 * DM)       // 3072

typedef __attribute__((ext_vector_type(8))) __bf16 bf16x8;
typedef __attribute__((ext_vector_type(4))) float  v4f;
typedef __attribute__((ext_vector_type(4))) _Float16 h4;
typedef __hip_bfloat16 bf16;

// ---- async global->LDS, 16B per lane ----
__device__ __forceinline__ void gld_lds16(const bf16* g, bf16* l) {
  __builtin_amdgcn_global_load_lds(
      (__attribute__((address_space(1))) void*)(g),
      (__attribute__((address_space(3))) void*)(l), 16, 0, 0);
}

// ---------------- cast fp32 -> bf16 (vectorized) ----------------
__global__ void cast_f32_bf16(const float* __restrict__ in, bf16* __restrict__ out) {
  int i = (blockIdx.x * 256 + threadIdx.x) * 4;
  float4 v = *(const float4*)(in + i);
  union { bf16 h[4]; ushort4 u; } r;
  r.h[0] = __float2bfloat16(v.x); r.h[1] = __float2bfloat16(v.y);
  r.h[2] = __float2bfloat16(v.z); r.h[3] = __float2bfloat16(v.w);
  *(ushort4*)(out + i) = r.u;
}

// ---------------- transpose + cast: in[R][C] fp32 -> out[C][R] bf16 ----------------
__global__ void transpose_cast(const float* __restrict__ in, bf16* __restrict__ out,
                               int R, int C) {
  __shared__ float tile[32][33];
  int c0 = blockIdx.x * 32, r0 = blockIdx.y * 32;
  int tx = threadIdx.x, ty = threadIdx.y;
  #pragma unroll
  for (int i = ty; i < 32; i += 8)
    tile[i][tx] = in[(size_t)(r0 + i) * C + c0 + tx];
  __syncthreads();
  #pragma unroll
  for (int i = ty; i < 32; i += 8)
    out[(size_t)(c0 + i) * R + r0 + tx] = __float2bfloat16(tile[tx][i]);
}

// ---------------- 128x128 BT-GEMM (A[M][K] bf16, BT[N][K] bf16) ----------------
// MODE 0: C fp32. MODE 1: QKV scatter (Q,K bf16 [bh][t][d]; V^T f16 [bh][d][t]).
template <int MODE>
__global__ __launch_bounds__(256) void gemm_bt(
    const bf16* __restrict__ A, const bf16* __restrict__ BT,
    float* __restrict__ Cf, bf16* __restrict__ qb, bf16* __restrict__ kb,
    __half* __restrict__ vtb, int M, int N, int K) {
  __shared__ bf16 As[128 * 64];   // [m][k], unpadded (global_load_lds constraint)
  __shared__ bf16 Bs[128 * 64];   // [n][k]
  const int tid = threadIdx.x;
  const int l = tid & 63, w = tid >> 6;
  const int wm = w >> 1, wn = w & 1;          // 2x2 wave grid, 64x64 C each
  const int m0 = blockIdx.y * 128, n0 = blockIdx.x * 128;
  const int fr = l & 15;                      // fragment row (m or n)
  const int fk = (l >> 4) * 8;                // fragment k offset

  v4f acc[4][4] = {};

  for (int kt = 0; kt < K; kt += 64) {
    __syncthreads();
    #pragma unroll
    for (int i = 0; i < 4; ++i) {
      int flat = (i * 256 + tid) * 8;         // LDS elem offset; lane-contiguous 16B
      int row = flat >> 6, col = flat & 63;
      gld_lds16(A + (size_t)(m0 + row) * K + kt + col, As + flat);
      gld_lds16(BT + (size_t)(n0 + row) * K + kt + col, Bs + flat);
    }
    __syncthreads();
    #pragma unroll
    for (int kk = 0; kk < 64; kk += 32) {
      bf16x8 af[4], bfr[4];
      #pragma unroll
      for (int i = 0; i < 4; ++i)
        af[i] = *(const bf16x8*)(As + (wm * 64 + i * 16 + fr) * 64 + kk + fk);
      #pragma unroll
      for (int i = 0; i < 4; ++i)
        bfr[i] = *(const bf16x8*)(Bs + (wn * 64 + i * 16 + fr) * 64 + kk + fk);
      #pragma unroll
      for (int mi = 0; mi < 4; ++mi)
        #pragma unroll
        for (int ni = 0; ni < 4; ++ni)
          acc[mi][ni] = __builtin_amdgcn_mfma_f32_16x16x32_bf16(
              af[mi], bfr[ni], acc[mi][ni], 0, 0, 0);
    }
  }

  // Epilogue. C/D layout: col = lane&15, row = (lane>>4)*4 + reg.
  #pragma unroll
  for (int mi = 0; mi < 4; ++mi) {
    #pragma unroll
    for (int ni = 0; ni < 4; ++ni) {
      #pragma unroll
      for (int r = 0; r < 4; ++r) {
        int gm = m0 + wm * 64 + mi * 16 + (l >> 4) * 4 + r;
        int gn = n0 + wn * 64 + ni * 16 + (l & 15);
        float v = acc[mi][ni][r];
        if constexpr (MODE == 0) {
          Cf[(size_t)gm * N + gn] = v;
        } else {
          int b = gm >> 11, t = gm & 2047;            // T=2048
          int s = gn >> 10, h = (gn >> 6) & 15, d = gn & 63;
          size_t bh = (size_t)(b * NH + h);
          if (s == 0)      qb[(bh * T_ + t) * HD + d] = __float2bfloat16(v);
          else if (s == 1) kb[(bh * T_ + t) * HD + d] = __float2bfloat16(v);
          else             vtb[(bh * HD + d) * T_ + t] = __float2half(v);
        }
      }
    }
  }
}

// ---------------- fused attention, S^T trick: P never touches LDS ----------------
// Compute S^T = K Q^T (A=K, B=Q, 16x16x32 bf16). C-layout of S^T gives lane l
// the values (key=(l>>4)*4+r, q=l&15) -- which is EXACTLY the A-operand layout
// (m=l&15, k=(l>>4)*4+j) of a 16x16x16 MFMA with m=q, k=key. So P = exp(S/64)
// is computed in-register and fed straight into PV (f16, V pre-converted),
// with the row-sum via a ones-B-fragment MFMA. No online softmax (muP 1/64
// scale bounds |s|, exp cannot overflow; softmax shift-invariant).
// Grid: (T/64, B*H). Block 128 (2 waves, 32 q-rows each). K-tile = 128.
__global__ __launch_bounds__(128) void flash_attn(
    const bf16* __restrict__ Qg, const bf16* __restrict__ Kg,
    const __half* __restrict__ VTg, bf16* __restrict__ Og) {
  __shared__ bf16   Ks[128][72];   // K tile [t'][d], row stride 144B (9*16)
  __shared__ __half Vs[64][136];   // V^T tile [d][t'] f16, row stride 272B (17*16)
  const int tid = threadIdx.x, l = tid & 63, w = tid >> 6;
  const int bh = blockIdx.y, qt = blockIdx.x;
  const int fr = l & 15, fk = (l >> 4) * 8, g4 = (l >> 4) * 4;
  const int q0 = qt * 64 + w * 32;
  const size_t base  = (size_t)bh * T_ * HD;   // Q/K base
  const size_t baseV = (size_t)bh * HD * T_;   // V^T base

  // Q fragments (B-operand of S^T: n=q, k=d) in registers, loaded once.
  bf16x8 qB[2][2];
  #pragma unroll
  for (int qf = 0; qf < 2; ++qf)
    #pragma unroll
    for (int kki = 0; kki < 2; ++kki)
      qB[qf][kki] = *(const bf16x8*)(
          Qg + base + (size_t)(q0 + qf * 16 + fr) * HD + kki * 32 + fk);

  h4 ones;
  #pragma unroll
  for (int j = 0; j < 4; ++j) ones[j] = (_Float16)1.0f;

  v4f o[2][4] = {};     // O accumulator: m=q (2 frags), n=d (4 frags)
  v4f lacc[2] = {};     // row sums via ones-MFMA

  for (int kt = 0; kt < T_; kt += 128) {
    __syncthreads();
    #pragma unroll
    for (int i = 0; i < 8; ++i) {
      int flat = (i * 128 + tid) * 8;          // 8192 elems per tile
      int kr = flat >> 6, kc = flat & 63;
      *(uint4*)(&Ks[kr][kc]) = *(const uint4*)(Kg + base + (size_t)(kt + kr) * HD + kc);
      int vr = flat >> 7, vc = flat & 127;
      *(uint4*)(&Vs[vr][vc]) = *(const uint4*)(VTg + baseV + (size_t)vr * T_ + kt + vc);
    }
    __syncthreads();

    // S^T = K Q^T : 128 keys (8 m-frags) x 32 q (2 n-frags) per wave
    v4f st[8][2] = {};
    #pragma unroll
    for (int kki = 0; kki < 2; ++kki) {
      #pragma unroll
      for (int kf = 0; kf < 8; ++kf) {
        bf16x8 ak = *(const bf16x8*)(&Ks[kf * 16 + fr][kki * 32 + fk]);
        #pragma unroll
        for (int qf = 0; qf < 2; ++qf)
          st[kf][qf] = __builtin_amdgcn_mfma_f32_16x16x32_bf16(
              ak, qB[qf][kki], st[kf][qf], 0, 0, 0);
      }
    }

    // P = exp(S/64) in-register (f16) -> feed as A of 16x16x16 f16 PV MFMAs.
    #pragma unroll
    for (int kf = 0; kf < 8; ++kf) {
      h4 ap[2];
      #pragma unroll
      for (int qf = 0; qf < 2; ++qf)
        #pragma unroll
        for (int r = 0; r < 4; ++r)
          ap[qf][r] = (_Float16)__expf(st[kf][qf][r] * 0.015625f);
      h4 bv[4];
      #pragma unroll
      for (int nf = 0; nf < 4; ++nf)
        bv[nf] = *(const h4*)(&Vs[nf * 16 + fr][kf * 16 + g4]);
      #pragma unroll
      for (int qf = 0; qf < 2; ++qf) {
        lacc[qf] = __builtin_amdgcn_mfma_f32_16x16x16f16(
            ap[qf], ones, lacc[qf], 0, 0, 0);
        #pragma unroll
        for (int nf = 0; nf < 4; ++nf)
          o[qf][nf] = __builtin_amdgcn_mfma_f32_16x16x16f16(
              ap[qf], bv[nf], o[qf][nf], 0, 0, 0);
      }
    }
  }

  // Epilogue: normalize, store attn[b][t][h*64+d] bf16
  int b = bh >> 4, h = bh & 15;
  #pragma unroll
  for (int qf = 0; qf < 2; ++qf) {
    #pragma unroll
    for (int r = 0; r < 4; ++r) {
      float inv = 1.f / lacc[qf][r];
      int t = q0 + qf * 16 + g4 + r;
      #pragma unroll
      for (int nf = 0; nf < 4; ++nf) {
        int d = nf * 16 + fr;
        Og[((size_t)(b * T_ + t)) * DM + h * HD + d] =
            __float2bfloat16(o[qf][nf][r] * inv);
      }
    }
  }
}

extern "C" void kernel_launch(void* const* d_in, const int* in_sizes, int n_in,
                              void* d_out, int out_size, void* d_ws, size_t ws_size,
                              hipStream_t stream) {
  const float* x     = (const float*)d_in[0];
  const float* Wqkv  = (const float*)d_in[1];
  const float* Wproj = (const float*)d_in[2];
  float* out = (float*)d_out;
  char* ws = (char*)d_ws;

  // Workspace layout (48 MB total)
  bf16*   Xb     = (bf16*)(ws);                        //  8 MB: X bf16 [4096][1024]
  bf16*   WqkvT  = (bf16*)(ws + (size_t)( 8u << 20));  //  6 MB: Wqkv^T [3072][1024]
  bf16*   WprojT = (bf16*)(ws + (size_t)(14u << 20));  //  2 MB: Wproj^T [1024][1024]
  bf16*   Qb     = (bf16*)(ws + (size_t)(16u << 20));  //  8 MB: Q [32][2048][64]
  bf16*   Kb     = (bf16*)(ws + (size_t)(24u << 20));  //  8 MB: K [32][2048][64]
  __half* VTh    = (__half*)(ws + (size_t)(32u << 20));//  8 MB: V^T f16 [32][64][2048]
  bf16*   Ab     = (bf16*)(ws + (size_t)(40u << 20));  //  8 MB: attn bf16 [4096][1024]

  cast_f32_bf16<<<(M_ * DM) / 1024, 256, 0, stream>>>(x, Xb);
  transpose_cast<<<dim3(N_QKV / 32, DM / 32), dim3(32, 8), 0, stream>>>(Wqkv, WqkvT, DM, N_QKV);
  transpose_cast<<<dim3(DM / 32, DM / 32), dim3(32, 8), 0, stream>>>(Wproj, WprojT, DM, DM);

  gemm_bt<1><<<dim3(N_QKV / 128, M_ / 128), 256, 0, stream>>>(
      Xb, WqkvT, nullptr, Qb, Kb, VTh, M_, N_QKV, DM);

  flash_attn<<<dim3(T_ / 64, B_ * NH), 128, 0, stream>>>(Qb, Kb, VTh, Ab);

  gemm_bt<0><<<dim3(DM / 128, M_ / 128), 256, 0, stream>>>(
      Ab, WprojT, out, nullptr, nullptr, nullptr, M_, DM, DM);
}

// Round 4
// 246.812 us; speedup vs baseline: 1.1630x; 1.1630x over previous
//
#include <hip/hip_runtime.h>
#include <hip/hip_bf16.h>
#include <hip/hip_fp16.h>
#include <stdint.h>

// Problem constants (B=2, T=2048, D=1024, H=16, hd=64)
#define B_    2
#define T_    2048
#define DM    1024
#define NH    16
#define HD    64
#define M_    (B_ * T_)      // 4096 rows of X
#define N_QKV (3 * DM)       // 3072

typedef __attribute__((ext_vector_type(8))) __bf16 bf16x8;
typedef __attribute__((ext_vector_type(4))) float  v4f;
typedef __attribute__((ext_vector_type(4))) _Float16 h4;
typedef __attribute__((ext_vector_type(8))) _Float16 h8;
typedef __hip_bfloat16 bf16;

// ---- async global->LDS, 16B per lane ----
__device__ __forceinline__ void gld_lds16(const bf16* g, bf16* l) {
  __builtin_amdgcn_global_load_lds(
      (__attribute__((address_space(1))) void*)(g),
      (__attribute__((address_space(3))) void*)(l), 16, 0, 0);
}

// ---------------- cast fp32 -> bf16 (vectorized) ----------------
__global__ void cast_f32_bf16(const float* __restrict__ in, bf16* __restrict__ out) {
  int i = (blockIdx.x * 256 + threadIdx.x) * 4;
  float4 v = *(const float4*)(in + i);
  union { bf16 h[4]; ushort4 u; } r;
  r.h[0] = __float2bfloat16(v.x); r.h[1] = __float2bfloat16(v.y);
  r.h[2] = __float2bfloat16(v.z); r.h[3] = __float2bfloat16(v.w);
  *(ushort4*)(out + i) = r.u;
}

// ---------------- transpose + cast: in[R][C] fp32 -> out[C][R] bf16 ----------------
__global__ void transpose_cast(const float* __restrict__ in, bf16* __restrict__ out,
                               int R, int C) {
  __shared__ float tile[32][33];
  int c0 = blockIdx.x * 32, r0 = blockIdx.y * 32;
  int tx = threadIdx.x, ty = threadIdx.y;
  #pragma unroll
  for (int i = ty; i < 32; i += 8)
    tile[i][tx] = in[(size_t)(r0 + i) * C + c0 + tx];
  __syncthreads();
  #pragma unroll
  for (int i = ty; i < 32; i += 8)
    out[(size_t)(c0 + i) * R + r0 + tx] = __float2bfloat16(tile[tx][i]);
}

// ---------------- 128x128 BT-GEMM (A[M][K] bf16, BT[N][K] bf16) ----------------
// MODE 0: C fp32. MODE 1: QKV scatter (Q,K bf16 [bh][t][d]; V^T f16 [bh][d][t]).
template <int MODE>
__global__ __launch_bounds__(256) void gemm_bt(
    const bf16* __restrict__ A, const bf16* __restrict__ BT,
    float* __restrict__ Cf, bf16* __restrict__ qb, bf16* __restrict__ kb,
    _Float16* __restrict__ vtb, int M, int N, int K) {
  __shared__ bf16 As[128 * 64];   // [m][k], unpadded (global_load_lds constraint)
  __shared__ bf16 Bs[128 * 64];   // [n][k]
  const int tid = threadIdx.x;
  const int l = tid & 63, w = tid >> 6;
  const int wm = w >> 1, wn = w & 1;          // 2x2 wave grid, 64x64 C each
  const int m0 = blockIdx.y * 128, n0 = blockIdx.x * 128;
  const int fr = l & 15;                      // fragment row (m or n)
  const int fk = (l >> 4) * 8;                // fragment k offset

  v4f acc[4][4] = {};

  for (int kt = 0; kt < K; kt += 64) {
    __syncthreads();
    #pragma unroll
    for (int i = 0; i < 4; ++i) {
      int flat = (i * 256 + tid) * 8;         // LDS elem offset; lane-contiguous 16B
      int row = flat >> 6, col = flat & 63;
      gld_lds16(A + (size_t)(m0 + row) * K + kt + col, As + flat);
      gld_lds16(BT + (size_t)(n0 + row) * K + kt + col, Bs + flat);
    }
    __syncthreads();
    #pragma unroll
    for (int kk = 0; kk < 64; kk += 32) {
      bf16x8 af[4], bfr[4];
      #pragma unroll
      for (int i = 0; i < 4; ++i)
        af[i] = *(const bf16x8*)(As + (wm * 64 + i * 16 + fr) * 64 + kk + fk);
      #pragma unroll
      for (int i = 0; i < 4; ++i)
        bfr[i] = *(const bf16x8*)(Bs + (wn * 64 + i * 16 + fr) * 64 + kk + fk);
      #pragma unroll
      for (int mi = 0; mi < 4; ++mi)
        #pragma unroll
        for (int ni = 0; ni < 4; ++ni)
          acc[mi][ni] = __builtin_amdgcn_mfma_f32_16x16x32_bf16(
              af[mi], bfr[ni], acc[mi][ni], 0, 0, 0);
    }
  }

  // Epilogue. C/D layout: col = lane&15, row = (lane>>4)*4 + reg.
  #pragma unroll
  for (int mi = 0; mi < 4; ++mi) {
    #pragma unroll
    for (int ni = 0; ni < 4; ++ni) {
      #pragma unroll
      for (int r = 0; r < 4; ++r) {
        int gm = m0 + wm * 64 + mi * 16 + (l >> 4) * 4 + r;
        int gn = n0 + wn * 64 + ni * 16 + (l & 15);
        float v = acc[mi][ni][r];
        if constexpr (MODE == 0) {
          Cf[(size_t)gm * N + gn] = v;
        } else {
          int b = gm >> 11, t = gm & 2047;            // T=2048
          int s = gn >> 10, h = (gn >> 6) & 15, d = gn & 63;
          size_t bh = (size_t)(b * NH + h);
          if (s == 0)      qb[(bh * T_ + t) * HD + d] = __float2bfloat16(v);
          else if (s == 1) kb[(bh * T_ + t) * HD + d] = __float2bfloat16(v);
          else             vtb[(bh * HD + d) * T_ + t] = (_Float16)v;
        }
      }
    }
  }
}

// ---------------- fused attention: S^T + packed-P LDS + full-rate K=32 PV ----------
// S^T = K Q^T (A=K, B=Q). Its C-layout gives lane l (key=(l>>4)*4+r, q=l&15):
// the 4 r-values are CONSECUTIVE KEYS, so storing P as Ps[q][key] packs them
// into one ds_write_b64 (h4 of exp). PV then reads A-frags as b128 (8
// contiguous keys = exact 16x16x32 A-layout) and runs full-rate f16 K=32
// MFMA. Ps is wave-private (32 q-rows per wave): no barrier, only in-wave
// lgkm ordering. No online softmax (muP 1/64 scale: exp can't overflow;
// softmax shift-invariant); row sums via ones-B MFMA.
// Grid: (T/128, B*H). Block 256 (4 waves, 32 q-rows each). K-tile = 128.
__global__ __launch_bounds__(256) void flash_attn(
    const bf16* __restrict__ Qg, const bf16* __restrict__ Kg,
    const _Float16* __restrict__ VTg, bf16* __restrict__ Og) {
  __shared__ bf16     Ks[128][72];    // K tile [t'][d], row 144B (9*16): 16B-aligned rows
  __shared__ _Float16 Vs[64][136];    // V^T tile [d][t'] f16, row 272B (17*16)
  __shared__ _Float16 Ps[128][136];   // P [q][key] f16, wave-private 32-row slabs
  const int tid = threadIdx.x, l = tid & 63, w = tid >> 6;
  const int bh = blockIdx.y, qt = blockIdx.x;
  const int fr = l & 15, fk = (l >> 4) * 8, g4 = (l >> 4) * 4;
  const int q0 = qt * 128 + w * 32;            // global first q-row of this wave
  const size_t base  = (size_t)bh * T_ * HD;   // Q/K base
  const size_t baseV = (size_t)bh * HD * T_;   // V^T base

  // Q fragments (B-operand of S^T: n=q, k=d) in registers, loaded once.
  bf16x8 qB[2][2];
  #pragma unroll
  for (int qf = 0; qf < 2; ++qf)
    #pragma unroll
    for (int kki = 0; kki < 2; ++kki)
      qB[qf][kki] = *(const bf16x8*)(
          Qg + base + (size_t)(q0 + qf * 16 + fr) * HD + kki * 32 + fk);

  h8 ones;
  #pragma unroll
  for (int j = 0; j < 8; ++j) ones[j] = (_Float16)1.0f;

  v4f o[2][4] = {};     // O accumulator: m=q (2 frags), n=d (4 frags)
  v4f lacc[2] = {};     // row sums via ones-MFMA

  for (int kt = 0; kt < T_; kt += 128) {
    __syncthreads();
    #pragma unroll
    for (int i = 0; i < 4; ++i) {
      int flat = (i * 256 + tid) * 8;          // 8192 elems per tile
      int kr = flat >> 6, kc = flat & 63;
      *(uint4*)(&Ks[kr][kc]) = *(const uint4*)(Kg + base + (size_t)(kt + kr) * HD + kc);
      int vr = flat >> 7, vc = flat & 127;
      *(uint4*)(&Vs[vr][vc]) = *(const uint4*)(VTg + baseV + (size_t)vr * T_ + kt + vc);
    }
    __syncthreads();

    // S^T per 16-key block, exp in-register, packed b64 store to Ps[q][key].
    #pragma unroll
    for (int kf = 0; kf < 8; ++kf) {
      v4f st[2] = {{0,0,0,0},{0,0,0,0}};
      #pragma unroll
      for (int kki = 0; kki < 2; ++kki) {
        bf16x8 ak = *(const bf16x8*)(&Ks[kf * 16 + fr][kki * 32 + fk]);
        #pragma unroll
        for (int qf = 0; qf < 2; ++qf)
          st[qf] = __builtin_amdgcn_mfma_f32_16x16x32_bf16(
              ak, qB[qf][kki], st[qf], 0, 0, 0);
      }
      #pragma unroll
      for (int qf = 0; qf < 2; ++qf) {
        h4 pv;
        #pragma unroll
        for (int r = 0; r < 4; ++r)
          pv[r] = (_Float16)__expf(st[qf][r] * 0.015625f);
        // lane's 4 values are keys kf*16+g4..+3 of q-row (w*32+qf*16+fr)
        *(h4*)(&Ps[w * 32 + qf * 16 + fr][kf * 16 + g4]) = pv;
      }
    }

    // O += P V (full-rate 16x16x32 f16); lacc += P * ones (row sums).
    #pragma unroll
    for (int kk = 0; kk < 4; ++kk) {
      h8 ap[2], bv[4];
      #pragma unroll
      for (int qf = 0; qf < 2; ++qf)
        ap[qf] = *(const h8*)(&Ps[w * 32 + qf * 16 + fr][kk * 32 + fk]);
      #pragma unroll
      for (int nf = 0; nf < 4; ++nf)
        bv[nf] = *(const h8*)(&Vs[nf * 16 + fr][kk * 32 + fk]);
      #pragma unroll
      for (int qf = 0; qf < 2; ++qf) {
        lacc[qf] = __builtin_amdgcn_mfma_f32_16x16x32_f16(
            ap[qf], ones, lacc[qf], 0, 0, 0);
        #pragma unroll
        for (int nf = 0; nf < 4; ++nf)
          o[qf][nf] = __builtin_amdgcn_mfma_f32_16x16x32_f16(
              ap[qf], bv[nf], o[qf][nf], 0, 0, 0);
      }
    }
  }

  // Epilogue: normalize, store attn[b][t][h*64+d] bf16
  int b = bh >> 4, h = bh & 15;
  #pragma unroll
  for (int qf = 0; qf < 2; ++qf) {
    #pragma unroll
    for (int r = 0; r < 4; ++r) {
      float inv = 1.f / lacc[qf][r];
      int t = q0 + qf * 16 + g4 + r;
      #pragma unroll
      for (int nf = 0; nf < 4; ++nf) {
        int d = nf * 16 + fr;
        Og[((size_t)(b * T_ + t)) * DM + h * HD + d] =
            __float2bfloat16(o[qf][nf][r] * inv);
      }
    }
  }
}

extern "C" void kernel_launch(void* const* d_in, const int* in_sizes, int n_in,
                              void* d_out, int out_size, void* d_ws, size_t ws_size,
                              hipStream_t stream) {
  const float* x     = (const float*)d_in[0];
  const float* Wqkv  = (const float*)d_in[1];
  const float* Wproj = (const float*)d_in[2];
  float* out = (float*)d_out;
  char* ws = (char*)d_ws;

  // Workspace layout (48 MB total)
  bf16*     Xb     = (bf16*)(ws);                        //  8 MB: X bf16 [4096][1024]
  bf16*     WqkvT  = (bf16*)(ws + (size_t)( 8u << 20));  //  6 MB: Wqkv^T [3072][1024]
  bf16*     WprojT = (bf16*)(ws + (size_t)(14u << 20));  //  2 MB: Wproj^T [1024][1024]
  bf16*     Qb     = (bf16*)(ws + (size_t)(16u << 20));  //  8 MB: Q [32][2048][64]
  bf16*     Kb     = (bf16*)(ws + (size_t)(24u << 20));  //  8 MB: K [32][2048][64]
  _Float16* VTh    = (_Float16*)(ws + (size_t)(32u << 20)); // 8 MB: V^T f16 [32][64][2048]
  bf16*     Ab     = (bf16*)(ws + (size_t)(40u << 20));  //  8 MB: attn bf16 [4096][1024]

  cast_f32_bf16<<<(M_ * DM) / 1024, 256, 0, stream>>>(x, Xb);
  transpose_cast<<<dim3(N_QKV / 32, DM / 32), dim3(32, 8), 0, stream>>>(Wqkv, WqkvT, DM, N_QKV);
  transpose_cast<<<dim3(DM / 32, DM / 32), dim3(32, 8), 0, stream>>>(Wproj, WprojT, DM, DM);

  gemm_bt<1><<<dim3(N_QKV / 128, M_ / 128), 256, 0, stream>>>(
      Xb, WqkvT, nullptr, Qb, Kb, VTh, M_, N_QKV, DM);

  flash_attn<<<dim3(T_ / 128, B_ * NH), 256, 0, stream>>>(Qb, Kb, VTh, Ab);

  gemm_bt<0><<<dim3(DM / 128, M_ / 128), 256, 0, stream>>>(
      Ab, WprojT, out, nullptr, nullptr, nullptr, M_, DM, DM);
}

// Round 6
// 243.870 us; speedup vs baseline: 1.1770x; 1.0121x over previous
//
#include <hip/hip_runtime.h>
#include <hip/hip_bf16.h>
#include <hip/hip_fp16.h>
#include <stdint.h>

// Problem constants (B=2, T=2048, D=1024, H=16, hd=64)
#define B_    2
#define T_    2048
#define DM    1024
#define NH    16
#define HD    64
#define M_    (B_ * T_)      // 4096 rows of X
#define N_QKV (3 * DM)       // 3072

typedef __attribute__((ext_vector_type(8))) __bf16 bf16x8;
typedef __attribute__((ext_vector_type(4))) float  v4f;
typedef __attribute__((ext_vector_type(4))) _Float16 h4;
typedef __attribute__((ext_vector_type(8))) _Float16 h8;
typedef __hip_bfloat16 bf16;

// ---- async global->LDS, 16B per lane (LDS dest must be lane-contiguous) ----
__device__ __forceinline__ void gld_lds16(const void* g, void* l) {
  __builtin_amdgcn_global_load_lds(
      (const __attribute__((address_space(1))) void*)(g),
      (__attribute__((address_space(3))) void*)(l), 16, 0, 0);
}

// ---------------- cast fp32 -> bf16 (vectorized) ----------------
__global__ void cast_f32_bf16(const float* __restrict__ in, bf16* __restrict__ out) {
  int i = (blockIdx.x * 256 + threadIdx.x) * 4;
  float4 v = *(const float4*)(in + i);
  union { bf16 h[4]; ushort4 u; } r;
  r.h[0] = __float2bfloat16(v.x); r.h[1] = __float2bfloat16(v.y);
  r.h[2] = __float2bfloat16(v.z); r.h[3] = __float2bfloat16(v.w);
  *(ushort4*)(out + i) = r.u;
}

// ---------------- transpose + cast: in[R][C] fp32 -> out[C][R] bf16 ----------------
__global__ void transpose_cast(const float* __restrict__ in, bf16* __restrict__ out,
                               int R, int C) {
  __shared__ float tile[32][33];
  int c0 = blockIdx.x * 32, r0 = blockIdx.y * 32;
  int tx = threadIdx.x, ty = threadIdx.y;
  #pragma unroll
  for (int i = ty; i < 32; i += 8)
    tile[i][tx] = in[(size_t)(r0 + i) * C + c0 + tx];
  __syncthreads();
  #pragma unroll
  for (int i = ty; i < 32; i += 8)
    out[(size_t)(c0 + i) * R + r0 + tx] = __float2bfloat16(tile[tx][i]);
}

// ---------------- transpose V: in[bh][t][d] f16 -> out[bh][d][t] f16 ----------------
// Coalesced both sides via a 64x64 LDS tile. Grid (T/64, B*H), block 256.
__global__ __launch_bounds__(256) void transpose_v(
    const _Float16* __restrict__ in, _Float16* __restrict__ out) {
  __shared__ _Float16 tl[64][72];   // +8 pad
  const int tid = threadIdx.x, bh = blockIdx.y, t0 = blockIdx.x * 64;
  const size_t ib = (size_t)bh * T_ * HD, ob = (size_t)bh * HD * T_;
  #pragma unroll
  for (int i = 0; i < 2; ++i) {
    int flat = (i * 256 + tid) * 8;   // 4096 elems total (64x64 tile)
    int r = flat >> 6, c = flat & 63;
    *(uint4*)(&tl[r][c]) = *(const uint4*)(in + ib + (size_t)(t0 + r) * HD + c);
  }
  __syncthreads();
  int d = tid >> 2, c0 = (tid & 3) * 16;
  #pragma unroll
  for (int j = 0; j < 16; j += 8) {
    union { _Float16 h[8]; uint4 u; } pk;
    #pragma unroll
    for (int k2 = 0; k2 < 8; ++k2) pk.h[k2] = tl[c0 + j + k2][d];
    *(uint4*)(out + ob + (size_t)d * T_ + t0 + c0 + j) = pk.u;
  }
}

// ---------------- 128x128 BT-GEMM (A[M][K] bf16, BT[N][K] bf16) ----------------
// MODE 0: C fp32. MODE 1: QKV scatter (Q,K bf16 [bh][t][d]; V f16 [bh][t][d] --
// all coalesced; V transposed later by transpose_v).
template <int MODE>
__global__ __launch_bounds__(256) void gemm_bt(
    const bf16* __restrict__ A, const bf16* __restrict__ BT,
    float* __restrict__ Cf, bf16* __restrict__ qb, bf16* __restrict__ kb,
    _Float16* __restrict__ vb, int M, int N, int K) {
  __shared__ bf16 As[128 * 64];   // [m][k], unpadded (global_load_lds constraint)
  __shared__ bf16 Bs[128 * 64];   // [n][k]
  const int tid = threadIdx.x;
  const int l = tid & 63, w = tid >> 6;
  const int wm = w >> 1, wn = w & 1;          // 2x2 wave grid, 64x64 C each
  const int m0 = blockIdx.y * 128, n0 = blockIdx.x * 128;
  const int fr = l & 15;                      // fragment row (m or n)
  const int fk = (l >> 4) * 8;                // fragment k offset

  v4f acc[4][4] = {};

  for (int kt = 0; kt < K; kt += 64) {
    __syncthreads();
    #pragma unroll
    for (int i = 0; i < 4; ++i) {
      int flat = (i * 256 + tid) * 8;         // LDS elem offset; lane-contiguous 16B
      int row = flat >> 6, col = flat & 63;
      gld_lds16(A + (size_t)(m0 + row) * K + kt + col, As + flat);
      gld_lds16(BT + (size_t)(n0 + row) * K + kt + col, Bs + flat);
    }
    __syncthreads();
    #pragma unroll
    for (int kk = 0; kk < 64; kk += 32) {
      bf16x8 af[4], bfr[4];
      #pragma unroll
      for (int i = 0; i < 4; ++i)
        af[i] = *(const bf16x8*)(As + (wm * 64 + i * 16 + fr) * 64 + kk + fk);
      #pragma unroll
      for (int i = 0; i < 4; ++i)
        bfr[i] = *(const bf16x8*)(Bs + (wn * 64 + i * 16 + fr) * 64 + kk + fk);
      #pragma unroll
      for (int mi = 0; mi < 4; ++mi)
        #pragma unroll
        for (int ni = 0; ni < 4; ++ni)
          acc[mi][ni] = __builtin_amdgcn_mfma_f32_16x16x32_bf16(
              af[mi], bfr[ni], acc[mi][ni], 0, 0, 0);
    }
  }

  // Epilogue. C/D layout: col = lane&15, row = (lane>>4)*4 + reg.
  #pragma unroll
  for (int mi = 0; mi < 4; ++mi) {
    #pragma unroll
    for (int ni = 0; ni < 4; ++ni) {
      #pragma unroll
      for (int r = 0; r < 4; ++r) {
        int gm = m0 + wm * 64 + mi * 16 + (l >> 4) * 4 + r;
        int gn = n0 + wn * 64 + ni * 16 + (l & 15);
        float v = acc[mi][ni][r];
        if constexpr (MODE == 0) {
          Cf[(size_t)gm * N + gn] = v;
        } else {
          int b = gm >> 11, t = gm & 2047;            // T=2048
          int s = gn >> 10, h = (gn >> 6) & 15, d = gn & 63;
          size_t bh = (size_t)(b * NH + h);
          if (s == 0)      qb[(bh * T_ + t) * HD + d] = __float2bfloat16(v);
          else if (s == 1) kb[(bh * T_ + t) * HD + d] = __float2bfloat16(v);
          else             vb[(bh * T_ + t) * HD + d] = (_Float16)v;
        }
      }
    }
  }
}

// ---------------- fused attention: S^T + chunked packed-P + K=32 f16 PV ----------
// S^T = K Q^T (A=K, B=Q): C-layout lane l holds (key=(l>>4)*4+r, q=l&15) with
// the 4 r-values CONSECUTIVE KEYS -> P=exp(S/64) packs into one ds_write_b64
// at Ps[q][key]. PV reads b128 A-frags (8 contiguous keys = 16x16x32 A-layout)
// and runs full-rate f16 K=32 MFMA. Ps is wave-private AND chunked to 32 keys
// (S^T -> exp -> PV per chunk), so LDS stays at 42.5KB -> 3 blocks/CU.
// No online softmax (muP 1/64: exp can't overflow; softmax shift-invariant);
// row sums via ones-B MFMA. Staging via global_load_lds (unpadded tiles).
// Grid: (T/128, B*H). Block 256 (4 waves, 32 q-rows each). K-tile = 128.
__global__ __launch_bounds__(256) void flash_attn(
    const bf16* __restrict__ Qg, const bf16* __restrict__ Kg,
    const _Float16* __restrict__ VTg, bf16* __restrict__ Og) {
  __shared__ bf16     Ks[128 * 64];   // K tile [t'][d], unpadded (16KB)
  __shared__ _Float16 Vs[64 * 128];   // V^T tile [d][t'] f16, unpadded (16KB)
  __shared__ _Float16 Ps[128][40];    // P [q][key%32] f16, wave-private (10KB)
  const int tid = threadIdx.x, l = tid & 63, w = tid >> 6;
  const int bh = blockIdx.y, qt = blockIdx.x;
  const int fr = l & 15, fk = (l >> 4) * 8, g4 = (l >> 4) * 4;
  const int q0 = qt * 128 + w * 32;            // global first q-row of this wave
  const size_t base  = (size_t)bh * T_ * HD;   // Q/K base
  const size_t baseV = (size_t)bh * HD * T_;   // V^T base

  // Q fragments (B-operand of S^T: n=q, k=d) in registers, loaded once.
  bf16x8 qB[2][2];
  #pragma unroll
  for (int qf = 0; qf < 2; ++qf)
    #pragma unroll
    for (int kki = 0; kki < 2; ++kki)
      qB[qf][kki] = *(const bf16x8*)(
          Qg + base + (size_t)(q0 + qf * 16 + fr) * HD + kki * 32 + fk);

  h8 ones;
  #pragma unroll
  for (int j = 0; j < 8; ++j) ones[j] = (_Float16)1.0f;

  v4f o[2][4] = {};     // O accumulator: m=q (2 frags), n=d (4 frags)
  v4f lacc[2] = {};     // row sums via ones-MFMA

  for (int kt = 0; kt < T_; kt += 128) {
    __syncthreads();
    // Each of Ks and Vs is 8192 elements: 4 iterations x 256 thr x 8 elems.
    #pragma unroll
    for (int i = 0; i < 4; ++i) {
      int flat = (i * 256 + tid) * 8;
      gld_lds16(Kg + base + (size_t)(kt + (flat >> 6)) * HD + (flat & 63), Ks + flat);
      gld_lds16(VTg + baseV + (size_t)(flat >> 7) * T_ + kt + (flat & 127), Vs + flat);
    }
    __syncthreads();

    // Process 4 chunks of 32 keys: S^T -> exp -> packed store -> PV.
    #pragma unroll
    for (int kk = 0; kk < 4; ++kk) {
      #pragma unroll
      for (int half = 0; half < 2; ++half) {
        const int kf = kk * 2 + half;
        v4f st[2] = {{0,0,0,0},{0,0,0,0}};
        #pragma unroll
        for (int kki = 0; kki < 2; ++kki) {
          bf16x8 ak = *(const bf16x8*)(Ks + (kf * 16 + fr) * 64 + kki * 32 + fk);
          #pragma unroll
          for (int qf = 0; qf < 2; ++qf)
            st[qf] = __builtin_amdgcn_mfma_f32_16x16x32_bf16(
                ak, qB[qf][kki], st[qf], 0, 0, 0);
        }
        #pragma unroll
        for (int qf = 0; qf < 2; ++qf) {
          h4 pv;
          #pragma unroll
          for (int r = 0; r < 4; ++r)
            pv[r] = (_Float16)__expf(st[qf][r] * 0.015625f);
          *(h4*)(&Ps[w * 32 + qf * 16 + fr][half * 16 + g4]) = pv;
        }
      }
      h8 ap[2], bv[4];
      #pragma unroll
      for (int qf = 0; qf < 2; ++qf)
        ap[qf] = *(const h8*)(&Ps[w * 32 + qf * 16 + fr][fk]);
      #pragma unroll
      for (int nf = 0; nf < 4; ++nf)
        bv[nf] = *(const h8*)(Vs + (nf * 16 + fr) * 128 + kk * 32 + fk);
      #pragma unroll
      for (int qf = 0; qf < 2; ++qf) {
        lacc[qf] = __builtin_amdgcn_mfma_f32_16x16x32_f16(
            ap[qf], ones, lacc[qf], 0, 0, 0);
        #pragma unroll
        for (int nf = 0; nf < 4; ++nf)
          o[qf][nf] = __builtin_amdgcn_mfma_f32_16x16x32_f16(
              ap[qf], bv[nf], o[qf][nf], 0, 0, 0);
      }
    }
  }

  // Epilogue: normalize, store attn[b][t][h*64+d] bf16
  int b = bh >> 4, h = bh & 15;
  #pragma unroll
  for (int qf = 0; qf < 2; ++qf) {
    #pragma unroll
    for (int r = 0; r < 4; ++r) {
      float inv = 1.f / lacc[qf][r];
      int t = q0 + qf * 16 + g4 + r;
      #pragma unroll
      for (int nf = 0; nf < 4; ++nf) {
        int d = nf * 16 + fr;
        Og[((size_t)(b * T_ + t)) * DM + h * HD + d] =
            __float2bfloat16(o[qf][nf][r] * inv);
      }
    }
  }
}

extern "C" void kernel_launch(void* const* d_in, const int* in_sizes, int n_in,
                              void* d_out, int out_size, void* d_ws, size_t ws_size,
                              hipStream_t stream) {
  const float* x     = (const float*)d_in[0];
  const float* Wqkv  = (const float*)d_in[1];
  const float* Wproj = (const float*)d_in[2];
  float* out = (float*)d_out;
  char* ws = (char*)d_ws;

  // Workspace layout (48 MB total). Region 40-48MB is double-used:
  // first as Vh (f16 V [bh][t][d], consumed by transpose_v), then as Ab
  // (flash output) -- flash only reads VTh/Qb/Kb, so the overlay is safe.
  bf16*     Xb     = (bf16*)(ws);                        //  8 MB: X bf16 [4096][1024]
  bf16*     WqkvT  = (bf16*)(ws + (size_t)( 8u << 20));  //  6 MB: Wqkv^T [3072][1024]
  bf16*     WprojT = (bf16*)(ws + (size_t)(14u << 20));  //  2 MB: Wproj^T [1024][1024]
  bf16*     Qb     = (bf16*)(ws + (size_t)(16u << 20));  //  8 MB: Q [32][2048][64]
  bf16*     Kb     = (bf16*)(ws + (size_t)(24u << 20));  //  8 MB: K [32][2048][64]
  _Float16* VTh    = (_Float16*)(ws + (size_t)(32u << 20)); // 8 MB: V^T f16 [32][64][2048]
  _Float16* Vh     = (_Float16*)(ws + (size_t)(40u << 20)); // 8 MB: V f16 [32][2048][64] (temp)
  bf16*     Ab     = (bf16*)(ws + (size_t)(40u << 20));  //  8 MB: attn bf16 [4096][1024]

  cast_f32_bf16<<<(M_ * DM) / 1024, 256, 0, stream>>>(x, Xb);
  transpose_cast<<<dim3(N_QKV / 32, DM / 32), dim3(32, 8), 0, stream>>>(Wqkv, WqkvT, DM, N_QKV);
  transpose_cast<<<dim3(DM / 32, DM / 32), dim3(32, 8), 0, stream>>>(Wproj, WprojT, DM, DM);

  gemm_bt<1><<<dim3(N_QKV / 128, M_ / 128), 256, 0, stream>>>(
      Xb, WqkvT, nullptr, Qb, Kb, Vh, M_, N_QKV, DM);

  transpose_v<<<dim3(T_ / 64, B_ * NH), 256, 0, stream>>>(Vh, VTh);

  flash_attn<<<dim3(T_ / 128, B_ * NH), 256, 0, stream>>>(Qb, Kb, VTh, Ab);

  gemm_bt<0><<<dim3(DM / 128, M_ / 128), 256, 0, stream>>>(
      Ab, WprojT, out, nullptr, nullptr, nullptr, M_, DM, DM);
}

// Round 7
// 215.071 us; speedup vs baseline: 1.3346x; 1.1339x over previous
//
#include <hip/hip_runtime.h>
#include <hip/hip_bf16.h>
#include <hip/hip_fp16.h>
#include <stdint.h>

// Problem constants (B=2, T=2048, D=1024, H=16, hd=64)
#define B_    2
#define T_    2048
#define DM    1024
#define NH    16
#define HD    64
#define M_    (B_ * T_)      // 4096 rows of X
#define N_QKV (3 * DM)       // 3072

typedef __attribute__((ext_vector_type(8))) __bf16 bf16x8;
typedef __attribute__((ext_vector_type(4))) float  v4f;
typedef __attribute__((ext_vector_type(4))) _Float16 h4;
typedef __attribute__((ext_vector_type(8))) _Float16 h8;
typedef __hip_bfloat16 bf16;

// ---- async global->LDS, 16B per lane (LDS dest must be lane-contiguous) ----
__device__ __forceinline__ void gld_lds16(const void* g, void* l) {
  __builtin_amdgcn_global_load_lds(
      (const __attribute__((address_space(1))) void*)(g),
      (__attribute__((address_space(3))) void*)(l), 16, 0, 0);
}

// XOR-swizzle note: LDS tiles staged by global_load_lds must be lane-
// contiguous, so rows can't be padded. Instead we permute 16B granules
// within each row: LDS granule g' holds global granule g = g' ^ (row & mask).
// Reads at fixed logical granule then hit banks rotated per row -> 2-way max
// alias (free, m136) instead of 16-way.

// ---------------- cast fp32 -> bf16 (vectorized) ----------------
__global__ void cast_f32_bf16(const float* __restrict__ in, bf16* __restrict__ out) {
  int i = (blockIdx.x * 256 + threadIdx.x) * 4;
  float4 v = *(const float4*)(in + i);
  union { bf16 h[4]; ushort4 u; } r;
  r.h[0] = __float2bfloat16(v.x); r.h[1] = __float2bfloat16(v.y);
  r.h[2] = __float2bfloat16(v.z); r.h[3] = __float2bfloat16(v.w);
  *(ushort4*)(out + i) = r.u;
}

// ---------------- transpose + cast: in[R][C] fp32 -> out[C][R] bf16 ----------------
__global__ void transpose_cast(const float* __restrict__ in, bf16* __restrict__ out,
                               int R, int C) {
  __shared__ float tile[32][33];
  int c0 = blockIdx.x * 32, r0 = blockIdx.y * 32;
  int tx = threadIdx.x, ty = threadIdx.y;
  #pragma unroll
  for (int i = ty; i < 32; i += 8)
    tile[i][tx] = in[(size_t)(r0 + i) * C + c0 + tx];
  __syncthreads();
  #pragma unroll
  for (int i = ty; i < 32; i += 8)
    out[(size_t)(c0 + i) * R + r0 + tx] = __float2bfloat16(tile[tx][i]);
}

// ---------------- transpose V: in[bh][t][d] f16 -> out[bh][d][t] f16 ----------------
__global__ __launch_bounds__(256) void transpose_v(
    const _Float16* __restrict__ in, _Float16* __restrict__ out) {
  __shared__ _Float16 tl[64][72];   // +8 pad
  const int tid = threadIdx.x, bh = blockIdx.y, t0 = blockIdx.x * 64;
  const size_t ib = (size_t)bh * T_ * HD, ob = (size_t)bh * HD * T_;
  #pragma unroll
  for (int i = 0; i < 2; ++i) {
    int flat = (i * 256 + tid) * 8;   // 4096 elems total (64x64 tile)
    int r = flat >> 6, c = flat & 63;
    *(uint4*)(&tl[r][c]) = *(const uint4*)(in + ib + (size_t)(t0 + r) * HD + c);
  }
  __syncthreads();
  int d = tid >> 2, c0 = (tid & 3) * 16;
  #pragma unroll
  for (int j = 0; j < 16; j += 8) {
    union { _Float16 h[8]; uint4 u; } pk;
    #pragma unroll
    for (int k2 = 0; k2 < 8; ++k2) pk.h[k2] = tl[c0 + j + k2][d];
    *(uint4*)(out + ob + (size_t)d * T_ + t0 + c0 + j) = pk.u;
  }
}

// ---------------- 128x128 BT-GEMM (A[M][K] bf16, BT[N][K] bf16) ----------------
// XOR-swizzled LDS tiles (8 granules/row). MODE 0: C fp32. MODE 1: QKV split
// (Q,K bf16 [bh][t][d]; V f16 [bh][t][d], transposed later by transpose_v).
template <int MODE>
__global__ __launch_bounds__(256) void gemm_bt(
    const bf16* __restrict__ A, const bf16* __restrict__ BT,
    float* __restrict__ Cf, bf16* __restrict__ qb, bf16* __restrict__ kb,
    _Float16* __restrict__ vb, int M, int N, int K) {
  __shared__ bf16 As[128 * 64];   // [m][g-swizzled k]
  __shared__ bf16 Bs[128 * 64];   // [n][g-swizzled k]
  const int tid = threadIdx.x;
  const int l = tid & 63, w = tid >> 6;
  const int wm = w >> 1, wn = w & 1;          // 2x2 wave grid, 64x64 C each
  const int m0 = blockIdx.y * 128, n0 = blockIdx.x * 128;
  const int fr = l & 15;                      // fragment row (m or n)
  const int lg = l >> 4;                      // lane granule group 0..3

  v4f acc[4][4] = {};

  for (int kt = 0; kt < K; kt += 64) {
    __syncthreads();
    #pragma unroll
    for (int i = 0; i < 4; ++i) {
      int p = i * 256 + tid;                  // granule index 0..1023
      int row = p >> 3, g = (p & 7) ^ (row & 7);
      gld_lds16(A + (size_t)(m0 + row) * K + kt + g * 8, As + p * 8);
      gld_lds16(BT + (size_t)(n0 + row) * K + kt + g * 8, Bs + p * 8);
    }
    __syncthreads();
    #pragma unroll
    for (int kk = 0; kk < 64; kk += 32) {
      const int gl = (kk >> 3) + lg;          // logical granule 0..7
      bf16x8 af[4], bfr[4];
      #pragma unroll
      for (int i = 0; i < 4; ++i) {
        int row = wm * 64 + i * 16 + fr;
        af[i] = *(const bf16x8*)(As + row * 64 + (gl ^ (fr & 7)) * 8);
      }
      #pragma unroll
      for (int i = 0; i < 4; ++i) {
        int row = wn * 64 + i * 16 + fr;
        bfr[i] = *(const bf16x8*)(Bs + row * 64 + (gl ^ (fr & 7)) * 8);
      }
      #pragma unroll
      for (int mi = 0; mi < 4; ++mi)
        #pragma unroll
        for (int ni = 0; ni < 4; ++ni)
          acc[mi][ni] = __builtin_amdgcn_mfma_f32_16x16x32_bf16(
              af[mi], bfr[ni], acc[mi][ni], 0, 0, 0);
    }
  }

  // Epilogue. C/D layout: col = lane&15, row = (lane>>4)*4 + reg.
  #pragma unroll
  for (int mi = 0; mi < 4; ++mi) {
    #pragma unroll
    for (int ni = 0; ni < 4; ++ni) {
      #pragma unroll
      for (int r = 0; r < 4; ++r) {
        int gm = m0 + wm * 64 + mi * 16 + (l >> 4) * 4 + r;
        int gn = n0 + wn * 64 + ni * 16 + (l & 15);
        float v = acc[mi][ni][r];
        if constexpr (MODE == 0) {
          Cf[(size_t)gm * N + gn] = v;
        } else {
          int b = gm >> 11, t = gm & 2047;            // T=2048
          int s = gn >> 10, h = (gn >> 6) & 15, d = gn & 63;
          size_t bh = (size_t)(b * NH + h);
          if (s == 0)      qb[(bh * T_ + t) * HD + d] = __float2bfloat16(v);
          else if (s == 1) kb[(bh * T_ + t) * HD + d] = __float2bfloat16(v);
          else             vb[(bh * T_ + t) * HD + d] = (_Float16)v;
        }
      }
    }
  }
}

// ---------------- fused attention: S^T + packed-P + K=32 f16 PV ----------
// S^T = K Q^T: C-layout lane l holds (key=(l>>4)*4+r, q=l&15); the 4 r-values
// are CONSECUTIVE KEYS -> P=exp(S/64) packs to one ds_write_b64 at Ps[q][key];
// PV reads b128 A-frags (8 contiguous keys = 16x16x32 f16 A-layout), full
// rate. No online softmax (muP 1/64: exp can't overflow; shift-invariant);
// row sums via ones-B MFMA. Ks/Vs staged by global_load_lds with XOR granule
// swizzle (conflict-free reads). 2 waves/block, wave q-tile 64 (4 m-frags):
// halves LDS instructions per query vs 32-row waves since K/V fragment reads
// amortize over 2x the q-rows. Grid (T/128, B*H), block 128, K-tile 128.
__global__ __launch_bounds__(128) void flash_attn(
    const bf16* __restrict__ Qg, const bf16* __restrict__ Kg,
    const _Float16* __restrict__ VTg, bf16* __restrict__ Og) {
  __shared__ bf16     Ks[128 * 64];   // K tile [t'][d], swizzled (16KB)
  __shared__ _Float16 Vs[64 * 128];   // V^T tile [d][t'] f16, swizzled (16KB)
  __shared__ _Float16 Ps[128][40];    // P [q][key%32] f16, wave-private (10KB)
  const int tid = threadIdx.x, l = tid & 63, w = tid >> 6;
  const int bh = blockIdx.y, qt = blockIdx.x;
  const int fr = l & 15, fk = (l >> 4) * 8, g4 = (l >> 4) * 4, lg = l >> 4;
  const int q0 = qt * 128 + w * 64;            // wave owns q-rows q0..q0+63
  const size_t base  = (size_t)bh * T_ * HD;   // Q/K base
  const size_t baseV = (size_t)bh * HD * T_;   // V^T base

  // Q fragments (B-operand of S^T: n=q, k=d) in registers, loaded once.
  bf16x8 qB[4][2];
  #pragma unroll
  for (int qf = 0; qf < 4; ++qf)
    #pragma unroll
    for (int kki = 0; kki < 2; ++kki)
      qB[qf][kki] = *(const bf16x8*)(
          Qg + base + (size_t)(q0 + qf * 16 + fr) * HD + kki * 32 + fk);

  h8 ones;
  #pragma unroll
  for (int j = 0; j < 8; ++j) ones[j] = (_Float16)1.0f;

  v4f o[4][4] = {};     // O accumulator: m=q (4 frags), n=d (4 frags)
  v4f lacc[4] = {};     // row sums via ones-MFMA

  for (int kt = 0; kt < T_; kt += 128) {
    __syncthreads();
    // 1024 granules each (Ks: 128 rows x 8 g; Vs: 64 rows x 16 g), 128 thr.
    #pragma unroll
    for (int i = 0; i < 8; ++i) {
      int p = i * 128 + tid;
      int krow = p >> 3, kg = (p & 7) ^ (krow & 7);
      gld_lds16(Kg + base + (size_t)(kt + krow) * HD + kg * 8, Ks + p * 8);
      int vrow = p >> 4, vg = (p & 15) ^ (vrow & 15);
      gld_lds16(VTg + baseV + (size_t)vrow * T_ + kt + vg * 8, Vs + p * 8);
    }
    __syncthreads();

    // 4 chunks of 32 keys: S^T -> exp -> packed store -> PV.
    #pragma unroll
    for (int kk = 0; kk < 4; ++kk) {
      #pragma unroll
      for (int half = 0; half < 2; ++half) {
        const int kf = kk * 2 + half;
        v4f st[4] = {};
        #pragma unroll
        for (int kki = 0; kki < 2; ++kki) {
          int row = kf * 16 + fr;
          bf16x8 ak = *(const bf16x8*)(
              Ks + row * 64 + ((kki * 4 + lg) ^ (fr & 7)) * 8);
          #pragma unroll
          for (int qf = 0; qf < 4; ++qf)
            st[qf] = __builtin_amdgcn_mfma_f32_16x16x32_bf16(
                ak, qB[qf][kki], st[qf], 0, 0, 0);
        }
        #pragma unroll
        for (int qf = 0; qf < 4; ++qf) {
          h4 pv;
          #pragma unroll
          for (int r = 0; r < 4; ++r)
            pv[r] = (_Float16)__expf(st[qf][r] * 0.015625f);
          *(h4*)(&Ps[w * 64 + qf * 16 + fr][half * 16 + g4]) = pv;
        }
      }
      h8 ap[4], bv[4];
      #pragma unroll
      for (int qf = 0; qf < 4; ++qf)
        ap[qf] = *(const h8*)(&Ps[w * 64 + qf * 16 + fr][fk]);
      #pragma unroll
      for (int nf = 0; nf < 4; ++nf) {
        int row = nf * 16 + fr;
        bv[nf] = *(const h8*)(Vs + row * 128 + ((kk * 4 + lg) ^ fr) * 8);
      }
      #pragma unroll
      for (int qf = 0; qf < 4; ++qf) {
        lacc[qf] = __builtin_amdgcn_mfma_f32_16x16x32_f16(
            ap[qf], ones, lacc[qf], 0, 0, 0);
        #pragma unroll
        for (int nf = 0; nf < 4; ++nf)
          o[qf][nf] = __builtin_amdgcn_mfma_f32_16x16x32_f16(
              ap[qf], bv[nf], o[qf][nf], 0, 0, 0);
      }
    }
  }

  // Epilogue: normalize, store attn[b][t][h*64+d] bf16
  int b = bh >> 4, h = bh & 15;
  #pragma unroll
  for (int qf = 0; qf < 4; ++qf) {
    #pragma unroll
    for (int r = 0; r < 4; ++r) {
      float inv = 1.f / lacc[qf][r];
      int t = q0 + qf * 16 + g4 + r;
      #pragma unroll
      for (int nf = 0; nf < 4; ++nf) {
        int d = nf * 16 + fr;
        Og[((size_t)(b * T_ + t)) * DM + h * HD + d] =
            __float2bfloat16(o[qf][nf][r] * inv);
      }
    }
  }
}

extern "C" void kernel_launch(void* const* d_in, const int* in_sizes, int n_in,
                              void* d_out, int out_size, void* d_ws, size_t ws_size,
                              hipStream_t stream) {
  const float* x     = (const float*)d_in[0];
  const float* Wqkv  = (const float*)d_in[1];
  const float* Wproj = (const float*)d_in[2];
  float* out = (float*)d_out;
  char* ws = (char*)d_ws;

  // Workspace layout (48 MB total). Region 40-48MB double-used: first Vh
  // (f16 V [bh][t][d], consumed by transpose_v), then Ab (flash output).
  bf16*     Xb     = (bf16*)(ws);                        //  8 MB
  bf16*     WqkvT  = (bf16*)(ws + (size_t)( 8u << 20));  //  6 MB
  bf16*     WprojT = (bf16*)(ws + (size_t)(14u << 20));  //  2 MB
  bf16*     Qb     = (bf16*)(ws + (size_t)(16u << 20));  //  8 MB
  bf16*     Kb     = (bf16*)(ws + (size_t)(24u << 20));  //  8 MB
  _Float16* VTh    = (_Float16*)(ws + (size_t)(32u << 20)); // 8 MB
  _Float16* Vh     = (_Float16*)(ws + (size_t)(40u << 20)); // 8 MB (temp)
  bf16*     Ab     = (bf16*)(ws + (size_t)(40u << 20));  //  8 MB (overlay)

  cast_f32_bf16<<<(M_ * DM) / 1024, 256, 0, stream>>>(x, Xb);
  transpose_cast<<<dim3(N_QKV / 32, DM / 32), dim3(32, 8), 0, stream>>>(Wqkv, WqkvT, DM, N_QKV);
  transpose_cast<<<dim3(DM / 32, DM / 32), dim3(32, 8), 0, stream>>>(Wproj, WprojT, DM, DM);

  gemm_bt<1><<<dim3(N_QKV / 128, M_ / 128), 256, 0, stream>>>(
      Xb, WqkvT, nullptr, Qb, Kb, Vh, M_, N_QKV, DM);

  transpose_v<<<dim3(T_ / 64, B_ * NH), 256, 0, stream>>>(Vh, VTh);

  flash_attn<<<dim3(T_ / 128, B_ * NH), 128, 0, stream>>>(Qb, Kb, VTh, Ab);

  gemm_bt<0><<<dim3(DM / 128, M_ / 128), 256, 0, stream>>>(
      Ab, WprojT, out, nullptr, nullptr, nullptr, M_, DM, DM);
}